// Round 1
// baseline (5584.352 us; speedup 1.0000x reference)
//
#include <hip/hip_runtime.h>
#include <math.h>

#define HW 65536
#define NPIX_PER_CH 524288.0f   // B*H*W

__device__ __forceinline__ float gelu_f(float v){
    return 0.5f * v * (1.0f + erff(v * 0.70710678118654752440f));
}

// ---------------- prep: zero stats + per-channel circular-conv kernel from fft_mask ----
__global__ void kzero(float* stats, int* fcnt){
    int t = threadIdx.x;
    if (t < 128) stats[t] = 0.f;
    if (t < 2)   fcnt[t]  = 0;
}

__global__ void kprep(const float* __restrict__ mask, float* __restrict__ kf,
                      int* __restrict__ flags, int* __restrict__ fcnt){
    __shared__ float ctS[8];
    const int c = blockIdx.x;      // 64 channels
    const int t = threadIdx.x;     // 64 threads = 1 wave; t = a*8+b
    if (t == 0){
        const float r = 0.70710678118654752440f;
        ctS[0]=1.f; ctS[1]=r; ctS[2]=0.f; ctS[3]=-r;
        ctS[4]=-1.f; ctS[5]=-r; ctS[6]=0.f; ctS[7]=r;
    }
    __syncthreads();
    const int a = t >> 3, b = t & 7;
    float s = 0.f;
    #pragma unroll
    for (int u=0; u<8; ++u){
        #pragma unroll
        for (int v=0; v<5; ++v){
            float wv = (v==0 || v==4) ? 1.f : 2.f;
            s += wv * mask[c*40 + u*5 + v] * ctS[(u*a + v*b) & 7];
        }
    }
    s *= (1.0f/64.0f);
    kf[c*64 + t] = s;
    float target = (t==0) ? 1.f : 0.f;
    int ok = (fabsf(s - target) < 1e-6f) ? 1 : 0;
    int allok = __all(ok);
    if (t == 0){ flags[c] = allok ? 1 : 0; atomicAdd(&fcnt[c>>5], allok ? 1 : 0); }
}

// ---------------- fused edffn: y = x + irfftmask(conv2(gate(dw(conv1(x))))) -----------
__global__ __launch_bounds__(256) void kfused(
    const float* __restrict__ x, const float* __restrict__ w_in, const float* __restrict__ b_in,
    const float* __restrict__ w_dw, const float* __restrict__ b_dw,
    const float* __restrict__ w_out, const float* __restrict__ b_out,
    const float* __restrict__ kf, const int* __restrict__ flags, const int* __restrict__ fcnt,
    float* __restrict__ yout)
{
    __shared__ float sm[15216];
    float* hS   = sm;            // [32][328]
    float* wtS  = sm + 10496;    // [64][32]  (k-major, transposed w_in chunk)
    float* xsS  = sm + 12544;    // [4][324]
    float* wdwS = sm + 13840;    // [32][9]
    float* bdwS = sm + 14128;    // [32]
    float* binS = sm + 14160;    // [32]
    float* wotS = sm + 14192;    // [16][64]
    float* slabS = sm;           // epilogue reuse: [32][256]
    float* kfS   = sm + 8192;    // epilogue reuse: [32][64]

    const int tid = threadIdx.x;
    const int bid = blockIdx.x;
    const int bb  = bid >> 8;                  // batch
    const int ty  = (bid >> 4) & 15, tx = bid & 15;
    const int gy0 = ty << 4, gx0 = tx << 4;

    const int cg = tid & 3, pg = tid >> 2;
    const int pA = pg << 2;
    const int pB = pA + 256;
    const bool hasB = (pB < 324);

    bool okA[4], okB[4];
    #pragma unroll
    for (int i=0;i<4;i++){
        int p = pA + i;
        int hy = (p*3641) >> 16; int hx = p - hy*18;
        int gy = gy0 - 1 + hy, gx = gx0 - 1 + hx;
        okA[i] = ((unsigned)gy < 256u) && ((unsigned)gx < 256u);
        p = pB + i;
        hy = (p*3641) >> 16; hx = p - hy*18;
        gy = gy0 - 1 + hy; gx = gx0 - 1 + hx;
        okB[i] = hasB && ((unsigned)gy < 256u) && ((unsigned)gx < 256u);
    }

    float acc[64];
    #pragma unroll
    for (int i=0;i<64;i++) acc[i] = 0.f;

    const int ly = tid >> 4, lx = tid & 15;
    const float* xB = x + (size_t)bb*64*HW;

    for (int cc=0; cc<16; ++cc){
        __syncthreads();   // (1) protect prior chunk's reads of weight/h buffers
        {   // w_in chunk, transposed into [k][jj]
            int jj = tid >> 3, k0 = (tid & 7) << 3;
            int ch = (jj < 16) ? (cc*16 + jj) : (256 + cc*16 + jj - 16);
            const float* wr = w_in + ch*64 + k0;
            #pragma unroll
            for (int i=0;i<8;i++) wtS[(k0+i)*32 + jj] = wr[i];
        }
        if (tid < 32){
            int jj = tid;
            int ch = (jj < 16) ? (cc*16 + jj) : (256 + cc*16 + jj - 16);
            binS[jj] = b_in[ch];
            bdwS[jj] = b_dw[ch];
            #pragma unroll
            for (int t2=0;t2<9;t2++) wdwS[jj*9+t2] = w_dw[ch*9+t2];
        }
        #pragma unroll
        for (int i=0;i<4;i++){
            int e = (tid<<2) + i; int g = e >> 6, oc = e & 63;
            wotS[e] = w_out[oc*256 + cc*16 + g];
        }
        __syncthreads();   // (2) weights visible

        float accA[32], accB[32];
        #pragma unroll
        for (int j=0;j<8;j++){
            float bv = binS[(cg<<3)+j];
            #pragma unroll
            for (int i=0;i<4;i++){ accA[j*4+i] = bv; accB[j*4+i] = bv; }
        }

        for (int ks=0; ks<16; ++ks){
            __syncthreads();   // (3) prior slice consumed
            #pragma unroll
            for (int kk=0; kk<4; ++kk){
                int k = (ks<<2) + kk;
                for (int p = tid; p < 324; p += 256){
                    int hy = (p*3641) >> 16; int hx = p - hy*18;
                    int gy = gy0 - 1 + hy, gx = gx0 - 1 + hx;
                    float v = 0.f;
                    if (((unsigned)gy < 256u) && ((unsigned)gx < 256u))
                        v = xB[k*HW + (gy<<8) + gx];
                    xsS[kk*324 + p] = v;
                }
            }
            __syncthreads();   // (4) slice visible
            #pragma unroll
            for (int kk=0; kk<4; ++kk){
                int k = (ks<<2) + kk;
                const float4 wa = *(const float4*)&wtS[k*32 + (cg<<3)];
                const float4 wb = *(const float4*)&wtS[k*32 + (cg<<3) + 4];
                const float4 xa = *(const float4*)&xsS[kk*324 + pA];
                float w8[8] = {wa.x,wa.y,wa.z,wa.w,wb.x,wb.y,wb.z,wb.w};
                float xv[4] = {xa.x,xa.y,xa.z,xa.w};
                #pragma unroll
                for (int j=0;j<8;j++){
                    #pragma unroll
                    for (int i=0;i<4;i++) accA[j*4+i] += w8[j]*xv[i];
                }
                if (hasB){
                    const float4 xb4 = *(const float4*)&xsS[kk*324 + pB];
                    float xw[4] = {xb4.x,xb4.y,xb4.z,xb4.w};
                    #pragma unroll
                    for (int j=0;j<8;j++){
                        #pragma unroll
                        for (int i=0;i<4;i++) accB[j*4+i] += w8[j]*xw[i];
                    }
                }
            }
        }
        // write h (zero outside image: SAME zero-padding happens in y1-space)
        #pragma unroll
        for (int j=0;j<8;j++){
            int row = ((cg<<3)+j)*328;
            float4 va = make_float4(okA[0]?accA[j*4+0]:0.f, okA[1]?accA[j*4+1]:0.f,
                                    okA[2]?accA[j*4+2]:0.f, okA[3]?accA[j*4+3]:0.f);
            *(float4*)&hS[row + pA] = va;
            if (hasB){
                float4 vb = make_float4(okB[0]?accB[j*4+0]:0.f, okB[1]?accB[j*4+1]:0.f,
                                        okB[2]?accB[j*4+2]:0.f, okB[3]?accB[j*4+3]:0.f);
                *(float4*)&hS[row + pB] = vb;
            }
        }
        __syncthreads();   // (5) h visible
        // stage 2: dwconv + gate + conv2 accumulate (thread = pixel)
        for (int g=0; g<16; ++g){
            const float* h1 = &hS[g*328];
            const float* h2 = &hS[(16+g)*328];
            const float* wd1 = &wdwS[g*9];
            const float* wd2 = &wdwS[(16+g)*9];
            float v1 = bdwS[g], v2 = bdwS[16+g];
            #pragma unroll
            for (int dy=0; dy<3; ++dy){
                int rb = (ly+dy)*18 + lx;
                #pragma unroll
                for (int dx=0; dx<3; ++dx){
                    v1 += wd1[dy*3+dx] * h1[rb+dx];
                    v2 += wd2[dy*3+dx] * h2[rb+dx];
                }
            }
            float aval = gelu_f(v1) * v2;
            #pragma unroll
            for (int oc=0; oc<64; oc+=4){
                float4 w4 = *(const float4*)&wotS[g*64 + oc];
                acc[oc+0] += w4.x*aval; acc[oc+1] += w4.y*aval;
                acc[oc+2] += w4.z*aval; acc[oc+3] += w4.w*aval;
            }
        }
    }

    // epilogue: per-patch circular conv (general) or passthrough (delta kernel), + residual
    const int pi = ly & 7, pj = lx & 7;
    const int pyb = ly & 8, pxb = lx & 8;
    const int gy = gy0 + ly, gx = gx0 + lx;
    #pragma unroll
    for (int s=0; s<2; ++s){
        int nfast = fcnt[s];
        if (nfast == 32){
            #pragma unroll
            for (int j=0;j<32;j++){
                int ch = s*32 + j;
                float o = acc[s*32+j] + b_out[ch];
                int gidx = ((bb*64+ch)<<16) + (gy<<8) + gx;
                yout[gidx] = o + x[gidx];
            }
        } else {
            __syncthreads();
            #pragma unroll
            for (int i=0;i<8;i++){ int e = tid + (i<<8); kfS[e] = kf[s*2048 + e]; }
            #pragma unroll
            for (int j=0;j<32;j++) slabS[j*256 + tid] = acc[s*32+j] + b_out[s*32+j];
            __syncthreads();
            #pragma unroll
            for (int j=0;j<32;j++){
                int ch = s*32 + j;
                float o;
                if (flags[ch]){
                    o = slabS[j*256 + tid];
                } else {
                    const float* kr = &kfS[j*64];
                    const float* sr = &slabS[j*256];
                    o = 0.f;
                    #pragma unroll
                    for (int a=0;a<8;a++){
                        int ii = (pi - a) & 7;
                        int rb2 = ((pyb + ii)<<4) + pxb;
                        #pragma unroll
                        for (int b2=0;b2<8;b2++){
                            int jj2 = (pj - b2) & 7;
                            o += kr[a*8+b2] * sr[rb2 + jj2];
                        }
                    }
                }
                int gidx = ((bb*64+ch)<<16) + (gy<<8) + gx;
                yout[gidx] = o + x[gidx];
            }
        }
    }
}

// ---------------- Scharr + batch stats --------------------------------------------------
__global__ __launch_bounds__(256) void kstats(const float* __restrict__ y,
    const float* __restrict__ swx, const float* __restrict__ swy,
    float* __restrict__ stats)
{
    __shared__ float yt[328];
    __shared__ float red[512];
    const int tid = threadIdx.x;
    const int bid = blockIdx.x;
    const int tile = bid & 255, c = (bid >> 8) & 63, bb = bid >> 14;
    const int ty = tile >> 4, tx = tile & 15;
    const int gy0 = ty<<4, gx0 = tx<<4;
    const float* yc = y + (size_t)((bb<<6) + c)*HW;
    for (int p = tid; p < 324; p += 256){
        int hy = (p*3641)>>16; int hx = p - hy*18;
        int gy = gy0 - 1 + hy, gx = gx0 - 1 + hx;
        float v = 0.f;
        if (((unsigned)gy<256u)&&((unsigned)gx<256u)) v = yc[(gy<<8)+gx];
        yt[p] = v;
    }
    __syncthreads();
    const int ly = tid>>4, lx = tid&15;
    float wx[9], wy[9];
    #pragma unroll
    for (int i=0;i<9;i++){ wx[i] = swx[c*9+i]; wy[i] = swy[c*9+i]; }
    float ex=0.f, ey=0.f;
    #pragma unroll
    for (int dy=0;dy<3;dy++){
        int rb = (ly+dy)*18 + lx;
        #pragma unroll
        for (int dx=0;dx<3;dx++){
            float v = yt[rb+dx];
            ex += wx[dy*3+dx]*v; ey += wy[dy*3+dx]*v;
        }
    }
    float es = sqrtf(ex*ex + ey*ey);
    red[tid] = es; red[256+tid] = es*es;
    __syncthreads();
    for (int st=128; st>0; st>>=1){
        if (tid < st){ red[tid] += red[tid+st]; red[256+tid] += red[256+tid+st]; }
        __syncthreads();
    }
    if (tid == 0){
        atomicAdd(&stats[c],    red[0]);
        atomicAdd(&stats[64+c], red[256]);
    }
}

// ---------------- BN + gelu gate -> out -------------------------------------------------
__global__ __launch_bounds__(256) void kfinal(const float* __restrict__ y,
    const float* __restrict__ swx, const float* __restrict__ swy,
    const float* __restrict__ stats, const float* __restrict__ gam,
    const float* __restrict__ bet, float* __restrict__ out)
{
    __shared__ float yt[328];
    const int tid = threadIdx.x;
    const int bid = blockIdx.x;
    const int tile = bid & 255, c = (bid >> 8) & 63, bb = bid >> 14;
    const int ty = tile >> 4, tx = tile & 15;
    const int gy0 = ty<<4, gx0 = tx<<4;
    const float* yc = y + (size_t)((bb<<6) + c)*HW;
    for (int p = tid; p < 324; p += 256){
        int hy = (p*3641)>>16; int hx = p - hy*18;
        int gy = gy0 - 1 + hy, gx = gx0 - 1 + hx;
        float v = 0.f;
        if (((unsigned)gy<256u)&&((unsigned)gx<256u)) v = yc[(gy<<8)+gx];
        yt[p] = v;
    }
    __syncthreads();
    const int ly = tid>>4, lx = tid&15;
    float wx[9], wy[9];
    #pragma unroll
    for (int i=0;i<9;i++){ wx[i] = swx[c*9+i]; wy[i] = swy[c*9+i]; }
    float ex=0.f, ey=0.f;
    #pragma unroll
    for (int dy=0;dy<3;dy++){
        int rb = (ly+dy)*18 + lx;
        #pragma unroll
        for (int dx=0;dx<3;dx++){
            float v = yt[rb+dx];
            ex += wx[dy*3+dx]*v; ey += wy[dy*3+dx]*v;
        }
    }
    float es = sqrtf(ex*ex + ey*ey);
    const float Ninv = 1.0f/NPIX_PER_CH;
    float mean = stats[c]*Ninv;
    float var  = stats[64+c]*Ninv - mean*mean;
    float n = (es - mean) / sqrtf(var + 1e-5f);
    n = n * gam[c] + bet[c];
    float att = gelu_f(n);
    int gy = gy0 + ly, gx = gx0 + lx;
    out[((size_t)((bb<<6)+c)<<16) + (gy<<8) + gx] = yt[(ly+1)*18 + (lx+1)] * att;
}

extern "C" void kernel_launch(void* const* d_in, const int* in_sizes, int n_in,
                              void* d_out, int out_size, void* d_ws, size_t ws_size,
                              hipStream_t stream)
{
    const float* x     = (const float*)d_in[0];
    const float* w_in  = (const float*)d_in[1];
    const float* b_in  = (const float*)d_in[2];
    const float* w_dw  = (const float*)d_in[3];
    const float* b_dw  = (const float*)d_in[4];
    const float* fmask = (const float*)d_in[5];
    const float* w_out = (const float*)d_in[6];
    const float* b_out = (const float*)d_in[7];
    const float* swx   = (const float*)d_in[8];
    const float* swy   = (const float*)d_in[9];
    const float* gam   = (const float*)d_in[10];
    const float* bet   = (const float*)d_in[11];
    float* out = (float*)d_out;

    float* Y     = (float*)d_ws;              // 33554432 floats (y = x + edffn(x))
    float* STATS = Y + 33554432;              // 128 floats
    float* KF    = STATS + 128;               // 64*64 floats
    int*   FLAGS = (int*)(KF + 4096);         // 64 ints
    int*   FCNT  = FLAGS + 64;                // 2 ints

    kzero <<<1,    256, 0, stream>>>(STATS, FCNT);
    kprep <<<64,    64, 0, stream>>>(fmask, KF, FLAGS, FCNT);
    kfused<<<2048, 256, 0, stream>>>(x, w_in, b_in, w_dw, b_dw, w_out, b_out,
                                     KF, FLAGS, FCNT, Y);
    kstats<<<131072,256,0, stream>>>(Y, swx, swy, STATS);
    kfinal<<<131072,256,0, stream>>>(Y, swx, swy, STATS, gam, bet, out);
}

// Round 2
// 2982.695 us; speedup vs baseline: 1.8723x; 1.8723x over previous
//
#include <hip/hip_runtime.h>
#include <math.h>

#define HW 65536
#define NPIXF 524288.0f   // B*H*W per channel

__device__ __forceinline__ float gelu_f(float v){
    return 0.5f * v * (1.0f + erff(v * 0.70710678118654752440f));
}

// ---------------- prep: zero stats + per-channel circular-conv kernel from fft_mask ----
__global__ void kzero(float* stats, int* fcnt){
    int t = threadIdx.x;
    if (t < 128) stats[t] = 0.f;
    if (t < 2)   fcnt[t]  = 0;
}

__global__ void kprep(const float* __restrict__ mask, float* __restrict__ kf,
                      int* __restrict__ flags, int* __restrict__ fcnt){
    __shared__ float ctS[8];
    const int c = blockIdx.x;      // 64 channels
    const int t = threadIdx.x;     // 64 threads = 1 wave; t = a*8+b
    if (t == 0){
        const float r = 0.70710678118654752440f;
        ctS[0]=1.f; ctS[1]=r; ctS[2]=0.f; ctS[3]=-r;
        ctS[4]=-1.f; ctS[5]=-r; ctS[6]=0.f; ctS[7]=r;
    }
    __syncthreads();
    const int a = t >> 3, b = t & 7;
    float s = 0.f;
    #pragma unroll
    for (int u=0; u<8; ++u){
        #pragma unroll
        for (int v=0; v<5; ++v){
            float wv = (v==0 || v==4) ? 1.f : 2.f;
            s += wv * mask[c*40 + u*5 + v] * ctS[(u*a + v*b) & 7];
        }
    }
    s *= (1.0f/64.0f);
    kf[c*64 + t] = s;
    float target = (t==0) ? 1.f : 0.f;
    int ok = (fabsf(s - target) < 1e-6f) ? 1 : 0;
    int allok = __all(ok);
    if (t == 0){ flags[c] = allok ? 1 : 0; atomicAdd(&fcnt[c>>5], allok ? 1 : 0); }
}

// ---------------- fused edffn: y = x + irfftmask(conv2(gate(dw(conv1(x))))) -----------
// LDS layout (floats):
//  xS   @0      : [64][324]  x halo, resident for whole kernel      (82944 B)
//  hS   @20736  : [32][328]  h chunk (halo stride 18, ch stride 328)(41984 B)
//  avS  @31232  : [16][260]  gated activations, interior 256 px     (16640 B)
//  wtS  @35392  : [64][32]   w_in chunk transposed                  ( 8192 B)
//  woS  @37440  : [16][64]   w_out chunk                            ( 4096 B)
//  wdS  @38464  : [32][9], bdS @38752[32], biS @38784[32], boS @38816[64]
//  total 38880 floats = 155520 B  (<=160KiB gfx950 workgroup LDS)
__global__ __launch_bounds__(256,1) void kfused(
    const float* __restrict__ x, const float* __restrict__ w_in, const float* __restrict__ b_in,
    const float* __restrict__ w_dw, const float* __restrict__ b_dw,
    const float* __restrict__ w_out, const float* __restrict__ b_out,
    const float* __restrict__ kf, const int* __restrict__ flags, const int* __restrict__ fcnt,
    float* __restrict__ yout)
{
    __shared__ float sm[38880];
    float* xS  = sm;
    float* hS  = sm + 20736;
    float* avS = sm + 31232;
    float* wtS = sm + 35392;
    float* woS = sm + 37440;
    float* wdS = sm + 38464;
    float* bdS = sm + 38752;
    float* biS = sm + 38784;
    float* boS = sm + 38816;
    float* slabS = hS;     // epilogue alias [32][256]
    float* kfS   = avS;    // epilogue alias [32][64]

    const int tid = threadIdx.x;
    const int bid = blockIdx.x;
    const int bb  = bid >> 8;
    const int gy0 = ((bid>>4)&15) << 4, gx0 = (bid&15) << 4;
    const float* xB = x + (size_t)bb*64*HW;

    // ---- stage x halo for all 64 channels (once) ----
    {
        int hp = tid;                       // < 324 always
        int hy = (hp*57)>>10, hx = hp - hy*18;
        int gy = gy0-1+hy, gx = gx0-1+hx;
        bool ok = ((unsigned)gy<256u) && ((unsigned)gx<256u);
        int off = (gy<<8)+gx;
        int hp2 = tid+256;
        int hy2 = (hp2*57)>>10, hx2 = hp2 - hy2*18;
        int gy2 = gy0-1+hy2, gx2 = gx0-1+hx2;
        bool has2 = hp2 < 324;
        bool ok2 = has2 && ((unsigned)gy2<256u) && ((unsigned)gx2<256u);
        int off2 = (gy2<<8)+gx2;
        for (int ch=0; ch<64; ++ch){
            float v = 0.f; if (ok) v = xB[ch*HW + off];
            xS[ch*324 + hp] = v;
            if (has2){
                float v2 = 0.f; if (ok2) v2 = xB[ch*HW + off2];
                xS[ch*324 + hp2] = v2;
            }
        }
        if (tid < 64) boS[tid] = b_out[tid];
    }

    // decomposition: wave-uniform channel group, lane-consecutive pixels
    const int cg = tid>>6;           // wave id 0..3
    const int pg = tid&63;
    const int pA = pg<<2, pB = pA+256;
    const bool hasB = (pB < 324);

    float mA[4], mB[4];
    #pragma unroll
    for (int i=0;i<4;i++){
        int p = pA+i; int hy=(p*57)>>10, hx=p-hy*18;
        int gy=gy0-1+hy, gx=gx0-1+hx;
        mA[i] = (((unsigned)gy<256u)&&((unsigned)gx<256u)) ? 1.f : 0.f;
        p = pB+i; if (p>323) p=323;
        hy=(p*57)>>10; hx=p-hy*18; gy=gy0-1+hy; gx=gx0-1+hx;
        mB[i] = (hasB && ((unsigned)gy<256u)&&((unsigned)gx<256u)) ? 1.f : 0.f;
    }

    float acc[64];
    #pragma unroll
    for (int i=0;i<64;i++) acc[i]=0.f;

    for (int cc=0; cc<16; ++cc){
        __syncthreads();   // prior chunk fully consumed
        // ---- stage weights for this chunk ----
        {
            int j = tid>>3, k0 = (tid&7)<<3;
            int ch = (j<16) ? (cc*16+j) : (240+cc*16+j);
            const float* wrg = w_in + ch*64 + k0;
            float4 a = *(const float4*)wrg;
            float4 b = *(const float4*)(wrg+4);
            wtS[(k0+0)*32+j]=a.x; wtS[(k0+1)*32+j]=a.y;
            wtS[(k0+2)*32+j]=a.z; wtS[(k0+3)*32+j]=a.w;
            wtS[(k0+4)*32+j]=b.x; wtS[(k0+5)*32+j]=b.y;
            wtS[(k0+6)*32+j]=b.z; wtS[(k0+7)*32+j]=b.w;
        }
        if (tid < 32){
            int ch = (tid<16) ? (cc*16+tid) : (240+cc*16+tid);
            biS[tid]=b_in[ch]; bdS[tid]=b_dw[ch];
            #pragma unroll
            for (int t2=0;t2<9;t2++) wdS[tid*9+t2] = w_dw[ch*9+t2];
        }
        #pragma unroll
        for (int i=0;i<4;i++){
            int e=(tid<<2)+i; int g=e>>6, oc=e&63;
            woS[e] = w_out[oc*256 + cc*16 + g];
        }
        __syncthreads();   // weights visible

        // ---- conv1: 8 ch (wave-uniform) x 8 px per thread, over k=0..63 ----
        float accA[32], accB[32];
        #pragma unroll
        for (int j=0;j<8;j++){
            float bv = biS[(cg<<3)+j];
            #pragma unroll
            for (int i=0;i<4;i++){ accA[j*4+i]=bv; accB[j*4+i]=bv; }
        }
        {
            const float* wr  = wtS + (cg<<3);
            const float* xrA = xS + pA;
            const float* xrB = xS + pB;   // may run past xS for !hasB lanes: in-bounds of sm, discarded
            #pragma unroll 4
            for (int k=0;k<64;++k){
                float4 w0 = *(const float4*)(wr + k*32);
                float4 w1 = *(const float4*)(wr + k*32 + 4);
                float4 xa = *(const float4*)(xrA + k*324);
                float4 xb = *(const float4*)(xrB + k*324);
                float wv[8] = {w0.x,w0.y,w0.z,w0.w,w1.x,w1.y,w1.z,w1.w};
                float va[4] = {xa.x,xa.y,xa.z,xa.w};
                float vb[4] = {xb.x,xb.y,xb.z,xb.w};
                #pragma unroll
                for (int j=0;j<8;j++){
                    #pragma unroll
                    for (int i=0;i<4;i++){
                        accA[j*4+i] += wv[j]*va[i];
                        accB[j*4+i] += wv[j]*vb[i];
                    }
                }
            }
        }
        // h store (zero outside image => SAME zero-pad in y1-space); lane-consecutive float4
        #pragma unroll
        for (int j=0;j<8;j++){
            float* row = hS + ((cg<<3)+j)*328;
            float4 va = make_float4(accA[j*4]*mA[0], accA[j*4+1]*mA[1],
                                    accA[j*4+2]*mA[2], accA[j*4+3]*mA[3]);
            *(float4*)(row + pA) = va;
            if (hasB){
                float4 vb = make_float4(accB[j*4]*mB[0], accB[j*4+1]*mB[1],
                                        accB[j*4+2]*mB[2], accB[j*4+3]*mB[3]);
                *(float4*)(row + pB) = vb;
            }
        }
        __syncthreads();   // h visible

        // ---- dw3x3 + gelu-gate -> avS (thread = interior pixel) ----
        {
            const int ly = tid>>4, lx = tid&15;
            #pragma unroll
            for (int g=0; g<16; ++g){
                const float* h1 = hS + g*328;
                const float* h2 = hS + (16+g)*328;
                const float* d1 = wdS + g*9;
                const float* d2 = wdS + (16+g)*9;
                float v1 = bdS[g], v2 = bdS[16+g];
                #pragma unroll
                for (int dy=0;dy<3;dy++){
                    int rb = (ly+dy)*18 + lx;
                    #pragma unroll
                    for (int dx=0;dx<3;dx++){
                        v1 += d1[dy*3+dx]*h1[rb+dx];
                        v2 += d2[dy*3+dx]*h2[rb+dx];
                    }
                }
                avS[g*260 + tid] = gelu_f(v1)*v2;
            }
        }
        __syncthreads();   // aval visible

        // ---- conv2: 16 oc (wave-uniform) x 4 px per thread ----
        #pragma unroll
        for (int g=0; g<16; ++g){
            float4 av = *(const float4*)(avS + g*260 + (pg<<2));
            float vv[4] = {av.x,av.y,av.z,av.w};
            #pragma unroll
            for (int o4=0;o4<4;++o4){
                float4 w4 = *(const float4*)(woS + g*64 + (cg<<4) + (o4<<2));
                float ww[4] = {w4.x,w4.y,w4.z,w4.w};
                #pragma unroll
                for (int jj=0;jj<4;jj++){
                    #pragma unroll
                    for (int i=0;i<4;i++) acc[(o4*4+jj)*4+i] += ww[jj]*vv[i];
                }
            }
        }
    }

    // ---- epilogue: FFT fast-path (delta kernel) or general circular conv; + residual ----
    __syncthreads();
    int nf0 = fcnt[0], nf1 = fcnt[1];
    const int p0 = pg<<2;
    const int prow = p0>>4, pcol = p0&15;
    const int gy = gy0+prow, gx = gx0+pcol;
    if (nf0==32 && nf1==32){
        #pragma unroll
        for (int o=0;o<16;++o){
            int oc = (cg<<4)+o;
            const float* xr = xS + oc*324 + (prow+1)*18 + (pcol+1);
            float bo = boS[oc];
            float4 v = make_float4(acc[o*4]+bo+xr[0], acc[o*4+1]+bo+xr[1],
                                   acc[o*4+2]+bo+xr[2], acc[o*4+3]+bo+xr[3]);
            *(float4*)&yout[(((bb<<6)+oc)<<16) + (gy<<8) + gx] = v;
        }
    } else {
        const int ly = tid>>4, lx = tid&15;
        const int pi = ly&7, pj = lx&7, pyb = ly&8, pxb = lx&8;
        for (int s=0;s<2;++s){
            __syncthreads();
            if ((cg>>1)==s){
                int ol = (cg&1)<<4;
                #pragma unroll
                for (int o=0;o<16;++o){
                    float bo = boS[s*32+ol+o];
                    float4 v = make_float4(acc[o*4]+bo, acc[o*4+1]+bo,
                                           acc[o*4+2]+bo, acc[o*4+3]+bo);
                    *(float4*)(slabS + (ol+o)*256 + p0) = v;
                }
            }
            #pragma unroll
            for (int it=0;it<8;++it) kfS[tid + (it<<8)] = kf[(s<<11) + tid + (it<<8)];
            __syncthreads();
            for (int j=0;j<32;++j){
                int ch = (s<<5)+j;
                float o;
                if (flags[ch]) o = slabS[j*256 + tid];
                else {
                    const float* kr = kfS + j*64;
                    const float* sr = slabS + j*256;
                    o = 0.f;
                    for (int a=0;a<8;++a){
                        int ii = (pi-a)&7;
                        int rb2 = ((pyb+ii)<<4) + pxb;
                        for (int b2=0;b2<8;++b2){
                            int jj2 = (pj-b2)&7;
                            o += kr[a*8+b2]*sr[rb2+jj2];
                        }
                    }
                }
                o += xS[ch*324 + (ly+1)*18 + (lx+1)];
                yout[(((bb<<6)+ch)<<16) + ((gy0+ly)<<8) + (gx0+lx)] = o;
            }
        }
    }
}

// ---------------- Scharr + batch stats, 32x32 tiles, writes es to ws --------------------
__global__ __launch_bounds__(256) void kstats32(const float* __restrict__ y,
    const float* __restrict__ swx, const float* __restrict__ swy,
    float* __restrict__ es_out, float* __restrict__ stats)
{
    __shared__ float yt[34*36];
    __shared__ float red[8];
    const int tid = threadIdx.x, bid = blockIdx.x;
    const int t = bid & 63, c = (bid>>6)&63, bb = bid>>12;
    const int gy0 = (t>>3)<<5, gx0 = (t&7)<<5;
    const float* yc = y + (size_t)((bb<<6)+c)*HW;
    for (int p = tid; p < 1156; p += 256){
        int hy = (p*1928)>>16; int hx = p - hy*34;
        int gy = gy0-1+hy, gx = gx0-1+hx;
        float v = 0.f;
        if (((unsigned)gy<256u)&&((unsigned)gx<256u)) v = yc[(gy<<8)+gx];
        yt[hy*36+hx] = v;
    }
    __syncthreads();
    float wx[9], wy[9];
    #pragma unroll
    for (int i=0;i<9;i++){ wx[i]=swx[c*9+i]; wy[i]=swy[c*9+i]; }
    const int r = tid>>3, cb = (tid&7)<<2;
    float w[3][6];
    #pragma unroll
    for (int dy=0;dy<3;dy++){
        #pragma unroll
        for (int j=0;j<6;j++) w[dy][j] = yt[(r+dy)*36 + cb + j];
    }
    float s1=0.f, s2=0.f; float e4[4];
    #pragma unroll
    for (int i=0;i<4;i++){
        float ex=0.f, ey=0.f;
        #pragma unroll
        for (int dy=0;dy<3;dy++){
            #pragma unroll
            for (int dx=0;dx<3;dx++){
                float vv = w[dy][i+dx];
                ex += wx[dy*3+dx]*vv; ey += wy[dy*3+dx]*vv;
            }
        }
        float es = sqrtf(ex*ex+ey*ey);
        e4[i]=es; s1+=es; s2+=es*es;
    }
    int gidx = (((bb<<6)+c)<<16) + ((gy0+r)<<8) + gx0+cb;
    *(float4*)&es_out[gidx] = make_float4(e4[0],e4[1],e4[2],e4[3]);
    #pragma unroll
    for (int off=32; off>0; off>>=1){
        s1 += __shfl_down(s1,off,64); s2 += __shfl_down(s2,off,64);
    }
    if ((tid&63)==0){ red[tid>>6]=s1; red[4+(tid>>6)]=s2; }
    __syncthreads();
    if (tid==0){
        atomicAdd(&stats[c],    red[0]+red[1]+red[2]+red[3]);
        atomicAdd(&stats[64+c], red[4]+red[5]+red[6]+red[7]);
    }
}

// ---------------- BN + gelu gate (elementwise, vectorized) ------------------------------
__global__ __launch_bounds__(256) void kfinalv(const float* __restrict__ Y,
    const float* __restrict__ ES, const float* __restrict__ stats,
    const float* __restrict__ gam, const float* __restrict__ bet,
    float* __restrict__ out)
{
    const int t = blockIdx.x*256 + threadIdx.x;
    const float Ninv = 1.0f/NPIXF;
    for (int it=0; it<16; ++it){
        int i4 = t + it*524288;
        int c = (i4 >> 14) & 63;
        float mean = stats[c]*Ninv;
        float var  = stats[64+c]*Ninv - mean*mean;
        float inv  = 1.0f/sqrtf(var + 1e-5f);
        float g = gam[c], b = bet[c];
        float4 y4 = ((const float4*)Y)[i4];
        float4 e4 = ((const float4*)ES)[i4];
        float4 r;
        r.x = y4.x * gelu_f((e4.x-mean)*inv*g + b);
        r.y = y4.y * gelu_f((e4.y-mean)*inv*g + b);
        r.z = y4.z * gelu_f((e4.z-mean)*inv*g + b);
        r.w = y4.w * gelu_f((e4.w-mean)*inv*g + b);
        ((float4*)out)[i4] = r;
    }
}

// ---------------- fallback (small ws): recompute-Scharr pair from R1 --------------------
__global__ __launch_bounds__(256) void kstats16(const float* __restrict__ y,
    const float* __restrict__ swx, const float* __restrict__ swy,
    float* __restrict__ stats)
{
    __shared__ float yt[328];
    __shared__ float red[512];
    const int tid = threadIdx.x;
    const int bid = blockIdx.x;
    const int tile = bid & 255, c = (bid >> 8) & 63, bb = bid >> 14;
    const int gy0 = (tile>>4)<<4, gx0 = (tile&15)<<4;
    const float* yc = y + (size_t)((bb<<6) + c)*HW;
    for (int p = tid; p < 324; p += 256){
        int hy = (p*57)>>10; int hx = p - hy*18;
        int gy = gy0 - 1 + hy, gx = gx0 - 1 + hx;
        float v = 0.f;
        if (((unsigned)gy<256u)&&((unsigned)gx<256u)) v = yc[(gy<<8)+gx];
        yt[p] = v;
    }
    __syncthreads();
    const int ly = tid>>4, lx = tid&15;
    float wx[9], wy[9];
    #pragma unroll
    for (int i=0;i<9;i++){ wx[i] = swx[c*9+i]; wy[i] = swy[c*9+i]; }
    float ex=0.f, ey=0.f;
    #pragma unroll
    for (int dy=0;dy<3;dy++){
        int rb = (ly+dy)*18 + lx;
        #pragma unroll
        for (int dx=0;dx<3;dx++){
            float v = yt[rb+dx];
            ex += wx[dy*3+dx]*v; ey += wy[dy*3+dx]*v;
        }
    }
    float es = sqrtf(ex*ex + ey*ey);
    red[tid] = es; red[256+tid] = es*es;
    __syncthreads();
    for (int st=128; st>0; st>>=1){
        if (tid < st){ red[tid] += red[tid+st]; red[256+tid] += red[256+tid+st]; }
        __syncthreads();
    }
    if (tid == 0){
        atomicAdd(&stats[c],    red[0]);
        atomicAdd(&stats[64+c], red[256]);
    }
}

__global__ __launch_bounds__(256) void kfinal16(const float* __restrict__ y,
    const float* __restrict__ swx, const float* __restrict__ swy,
    const float* __restrict__ stats, const float* __restrict__ gam,
    const float* __restrict__ bet, float* __restrict__ out)
{
    __shared__ float yt[328];
    const int tid = threadIdx.x;
    const int bid = blockIdx.x;
    const int tile = bid & 255, c = (bid >> 8) & 63, bb = bid >> 14;
    const int gy0 = (tile>>4)<<4, gx0 = (tile&15)<<4;
    const float* yc = y + (size_t)((bb<<6) + c)*HW;
    for (int p = tid; p < 324; p += 256){
        int hy = (p*57)>>10; int hx = p - hy*18;
        int gy = gy0 - 1 + hy, gx = gx0 - 1 + hx;
        float v = 0.f;
        if (((unsigned)gy<256u)&&((unsigned)gx<256u)) v = yc[(gy<<8)+gx];
        yt[p] = v;
    }
    __syncthreads();
    const int ly = tid>>4, lx = tid&15;
    float wx[9], wy[9];
    #pragma unroll
    for (int i=0;i<9;i++){ wx[i] = swx[c*9+i]; wy[i] = swy[c*9+i]; }
    float ex=0.f, ey=0.f;
    #pragma unroll
    for (int dy=0;dy<3;dy++){
        int rb = (ly+dy)*18 + lx;
        #pragma unroll
        for (int dx=0;dx<3;dx++){
            float v = yt[rb+dx];
            ex += wx[dy*3+dx]*v; ey += wy[dy*3+dx]*v;
        }
    }
    float es = sqrtf(ex*ex + ey*ey);
    const float Ninv = 1.0f/NPIXF;
    float mean = stats[c]*Ninv;
    float var  = stats[64+c]*Ninv - mean*mean;
    float n = (es - mean) / sqrtf(var + 1e-5f);
    n = n * gam[c] + bet[c];
    float att = gelu_f(n);
    int gy = gy0 + ly, gx = gx0 + lx;
    out[((size_t)((bb<<6)+c)<<16) + (gy<<8) + gx] = yt[(ly+1)*18 + (lx+1)] * att;
}

extern "C" void kernel_launch(void* const* d_in, const int* in_sizes, int n_in,
                              void* d_out, int out_size, void* d_ws, size_t ws_size,
                              hipStream_t stream)
{
    const float* x     = (const float*)d_in[0];
    const float* w_in  = (const float*)d_in[1];
    const float* b_in  = (const float*)d_in[2];
    const float* w_dw  = (const float*)d_in[3];
    const float* b_dw  = (const float*)d_in[4];
    const float* fmask = (const float*)d_in[5];
    const float* w_out = (const float*)d_in[6];
    const float* b_out = (const float*)d_in[7];
    const float* swx   = (const float*)d_in[8];
    const float* swy   = (const float*)d_in[9];
    const float* gam   = (const float*)d_in[10];
    const float* bet   = (const float*)d_in[11];
    float* out = (float*)d_out;

    const size_t nY = 33554432ull;
    const size_t need_full = (2*nY + 128 + 4096 + 64 + 2)*4 + 256;
    const bool full = (ws_size >= need_full);

    float* Y     = (float*)d_ws;
    float* ES    = Y + nY;
    float* STATS = full ? (ES + nY) : (Y + nY);
    float* KF    = STATS + 128;
    int*   FLAGS = (int*)(KF + 4096);
    int*   FCNT  = FLAGS + 64;

    kzero <<<1,   256, 0, stream>>>(STATS, FCNT);
    kprep <<<64,   64, 0, stream>>>(fmask, KF, FLAGS, FCNT);
    kfused<<<2048,256, 0, stream>>>(x, w_in, b_in, w_dw, b_dw, w_out, b_out,
                                    KF, FLAGS, FCNT, Y);
    if (full){
        kstats32<<<32768, 256, 0, stream>>>(Y, swx, swy, ES, STATS);
        kfinalv <<<2048,  256, 0, stream>>>(Y, ES, STATS, gam, bet, out);
    } else {
        kstats16<<<131072,256, 0, stream>>>(Y, swx, swy, STATS);
        kfinal16<<<131072,256, 0, stream>>>(Y, swx, swy, STATS, gam, bet, out);
    }
}